// Round 6
// baseline (115.906 us; speedup 1.0000x reference)
//
#include <hip/hip_runtime.h>
#include <hip/hip_bf16.h>

#ifndef __has_builtin
#define __has_builtin(x) 0
#endif

// ---- problem constants ----
constexpr int B_ = 8, TE_ = 512, TD_ = 128, H_ = 256;
constexpr float TWO_LOG2E = 2.8853900817779268f;   // 2*log2(e)
constexpr float LOG2E = 1.4426950408889634f;

typedef float  vf2    __attribute__((ext_vector_type(2)));
typedef short  bf16x8 __attribute__((ext_vector_type(8)));
typedef float  f32x4  __attribute__((ext_vector_type(4)));

__device__ __forceinline__ float exp2_fast(float x) {
#if __has_builtin(__builtin_amdgcn_exp2f)
  return __builtin_amdgcn_exp2f(x);     // v_exp_f32 (quarter rate)
#else
  return exp2f(x);
#endif
}
__device__ __forceinline__ float rcp_fast(float x) {
#if __has_builtin(__builtin_amdgcn_rcpf)
  return __builtin_amdgcn_rcpf(x);      // v_rcp_f32 (quarter rate)
#else
  return 1.0f / x;
#endif
}
__device__ __forceinline__ vf2 fma2(vf2 a, vf2 b, vf2 c) {
#if __has_builtin(__builtin_elementwise_fma)
  return __builtin_elementwise_fma(a, b, c);   // v_pk_fma_f32
#else
  vf2 r; r.x = __fmaf_rn(a.x, b.x, c.x); r.y = __fmaf_rn(a.y, b.y, c.y); return r;
#endif
}
// split fp32 -> bf16 hi + bf16 lo (x ~= hi + lo to ~2^-16 rel)
__device__ __forceinline__ void bf16split(float x, unsigned short& hi, unsigned short& lo) {
  unsigned u = __float_as_uint(x);
  hi = (unsigned short)(u >> 16);
  float hif = __uint_as_float((unsigned)hi << 16);
  lo = (unsigned short)(__float_as_uint(x - hif) >> 16);
}

// ================= MFMA projection: ep=(enc@W)*c, dp=(dec@U)*c =================
// Split-bf16 (3 products). Block tile 32m x 32n, 4 waves (one 16x16 C tile each),
// K chunks of 32. grid (160, 8) = 1280 blocks.  [unchanged — proven]
__global__ __launch_bounds__(256)
void proj_mfma(const float* __restrict__ enc, const float* __restrict__ dec,
               const float* __restrict__ W, const float* __restrict__ U,
               float* __restrict__ ep, float* __restrict__ dp) {
  __shared__ unsigned short Ah[32][40], Al[32][40], Bh[32][40], Bl[32][40];
  const int tid = threadIdx.x;
  const int mt = blockIdx.x;
  const int n0 = blockIdx.y * 32;
  const float* A; const float* Bm; float* C; int row0;
  if (mt < 128) { A = enc; Bm = W; C = ep; row0 = mt * 32; }
  else          { A = dec; Bm = U; C = dp; row0 = (mt - 128) * 32; }
  const int w = tid >> 6, lane = tid & 63;
  const int mw = (w & 1) * 16, nw = (w >> 1) * 16;
  const int quad = lane >> 4, l16 = lane & 15;
  const int am = tid >> 3, ak = (tid & 7) * 4;
  const int bn = tid & 31, bk = (tid >> 5) * 4;

  f32x4 acc = {0.f, 0.f, 0.f, 0.f};
  for (int k0 = 0; k0 < H_; k0 += 32) {
    float4 a4 = *(const float4*)&A[(long)(row0 + am) * H_ + k0 + ak];
    unsigned short h0, l0, h1, l1, h2, l2, h3, l3;
    bf16split(a4.x, h0, l0); bf16split(a4.y, h1, l1);
    bf16split(a4.z, h2, l2); bf16split(a4.w, h3, l3);
    *(ushort4*)&Ah[am][ak] = make_ushort4(h0, h1, h2, h3);
    *(ushort4*)&Al[am][ak] = make_ushort4(l0, l1, l2, l3);
    float b0 = Bm[(long)(k0 + bk + 0) * H_ + n0 + bn];
    float b1 = Bm[(long)(k0 + bk + 1) * H_ + n0 + bn];
    float b2 = Bm[(long)(k0 + bk + 2) * H_ + n0 + bn];
    float b3 = Bm[(long)(k0 + bk + 3) * H_ + n0 + bn];
    bf16split(b0, h0, l0); bf16split(b1, h1, l1);
    bf16split(b2, h2, l2); bf16split(b3, h3, l3);
    *(ushort4*)&Bh[bn][bk] = make_ushort4(h0, h1, h2, h3);
    *(ushort4*)&Bl[bn][bk] = make_ushort4(l0, l1, l2, l3);
    __syncthreads();
    bf16x8 ah = *(const bf16x8*)&Ah[mw + l16][quad * 8];
    bf16x8 al = *(const bf16x8*)&Al[mw + l16][quad * 8];
    bf16x8 bh = *(const bf16x8*)&Bh[nw + l16][quad * 8];
    bf16x8 bl = *(const bf16x8*)&Bl[nw + l16][quad * 8];
    acc = __builtin_amdgcn_mfma_f32_16x16x32_bf16(ah, bh, acc, 0, 0, 0);
    acc = __builtin_amdgcn_mfma_f32_16x16x32_bf16(ah, bl, acc, 0, 0, 0);
    acc = __builtin_amdgcn_mfma_f32_16x16x32_bf16(al, bh, acc, 0, 0, 0);
    __syncthreads();
  }
#pragma unroll
  for (int r = 0; r < 4; ++r)
    C[(long)(row0 + mw + quad * 4 + r) * H_ + n0 + nw + l16] = acc[r] * TWO_LOG2E;
}

// ================= score kernel, h-split  [unchanged — at VALU floor] ==========
// Partial sc over h-half: blockIdx.z = b*2 + hs. sc is [2][B][TD][TE].
__global__ __launch_bounds__(256)
void score_kernel(const float* __restrict__ ep, const float* __restrict__ dp,
                  const float* __restrict__ v, float* __restrict__ sc) {
  __shared__ __align__(16) float eps[32][68];
  __shared__ __align__(16) float dps[16][68];
  __shared__ __align__(16) float vs[64];
  const int tid = threadIdx.x;
  const int bz = blockIdx.z;
  const int b = bz >> 1;
  const int h_lo = (bz & 1) * 128;
  const int e0 = blockIdx.x * 32;
  const int d0 = blockIdx.y * 16;
  const int e = tid & 31;
  const int dg = tid >> 5;
  vf2 acc0 = {0.f, 0.f}, acc1 = {0.f, 0.f};

  for (int h0 = h_lo; h0 < h_lo + 128; h0 += 64) {
#pragma unroll
    for (int i = 0; i < 2; ++i) {
      int idx = tid + i * 256;
      int r = idx >> 4, c = (idx & 15) << 2;
      *(float4*)&eps[r][c] = *(const float4*)&ep[(long)(b * TE_ + e0 + r) * H_ + h0 + c];
    }
    {
      int r = tid >> 4, c = (tid & 15) << 2;
      *(float4*)&dps[r][c] = *(const float4*)&dp[(long)(b * TD_ + d0 + r) * H_ + h0 + c];
    }
    if (tid < 16) {
      float4 v4 = *(const float4*)&v[h0 + tid * 4];
      float4 o; o.x = -2.f * v4.x; o.y = -2.f * v4.y; o.z = -2.f * v4.z; o.w = -2.f * v4.w;
      *(float4*)&vs[tid * 4] = o;
    }
    __syncthreads();
    const vf2 one2 = {1.f, 1.f};
#pragma unroll
    for (int hh = 0; hh < 64; hh += 4) {
      float4 evf = *(const float4*)&eps[e][hh];
      float4 vvf = *(const float4*)&vs[hh];
      float4 daf = *(const float4*)&dps[dg * 2 + 0][hh];
      float4 dbf = *(const float4*)&dps[dg * 2 + 1][hh];
      vf2 ev0 = {evf.x, evf.y}, ev1 = {evf.z, evf.w};
      vf2 vv0 = {vvf.x, vvf.y}, vv1 = {vvf.z, vvf.w};
      vf2 da0 = {daf.x, daf.y}, da1 = {daf.z, daf.w};
      vf2 db0 = {dbf.x, dbf.y}, db1 = {dbf.z, dbf.w};
      vf2 g0 = ev0 + da0, g1 = ev1 + da1;
      vf2 h0v = ev0 + db0, h1v = ev1 + db1;
      vf2 t0, t1, u0, u1;
      t0.x = exp2_fast(g0.x); t0.y = exp2_fast(g0.y);
      t1.x = exp2_fast(g1.x); t1.y = exp2_fast(g1.y);
      u0.x = exp2_fast(h0v.x); u0.y = exp2_fast(h0v.y);
      u1.x = exp2_fast(h1v.x); u1.y = exp2_fast(h1v.y);
      t0 = t0 + one2; t1 = t1 + one2; u0 = u0 + one2; u1 = u1 + one2;
      vf2 r0, r1, s0, s1;
      r0.x = rcp_fast(t0.x); r0.y = rcp_fast(t0.y);
      r1.x = rcp_fast(t1.x); r1.y = rcp_fast(t1.y);
      s0.x = rcp_fast(u0.x); s0.y = rcp_fast(u0.y);
      s1.x = rcp_fast(u1.x); s1.y = rcp_fast(u1.y);
      acc0 = fma2(vv0, r0, acc0); acc0 = fma2(vv1, r1, acc0);
      acc1 = fma2(vv0, s0, acc1); acc1 = fma2(vv1, s1, acc1);
    }
    __syncthreads();
  }
  long base = ((long)(bz & 1) * B_ * TD_ + (long)b * TD_ + d0 + dg * 2) * TE_ + e0 + e;
  sc[base] = acc0.x + acc0.y;
  sc[base + TE_] = acc1.x + acc1.y;
}

// ============ fused softmax + context MFMA (replaces softmax + ctx_mfma) ========
// grid (TD/32=4, H/32=8, B=8) = 256 blocks, 256 threads = 4 waves.
// Phase 1: per-row softmax stats over x = sc_half0 + sc_half1 (wave w: rows w*8..+7);
//          rowc[r] = -m*log2e - log2(sum) so weight p = exp2(x*log2e + rowc).
// Phase 2: K-loop stages P (normalized weights) straight into the MFMA A-tile
//          (split-bf16); blocks with n0==0 also write P to the attn output.
//          B = enc split-bf16; 3-product MFMA.
__global__ __launch_bounds__(256)
void ctx_sm(const float* __restrict__ sc, const float* __restrict__ enc,
            float* __restrict__ attn, float* __restrict__ ctx) {
  __shared__ unsigned short Ph[32][40], Pl[32][40], Eh[32][40], El[32][40];
  __shared__ float rowc[32];
  const int tid = threadIdx.x;
  const int m0 = blockIdx.x * 32;
  const int n0 = blockIdx.y * 32;
  const int b  = blockIdx.z;
  const int w = tid >> 6, lane = tid & 63;
  const float* s0 = sc + ((long)b * TD_ + m0) * TE_;                 // half 0
  const float* s1 = sc + ((long)B_ * TD_ + (long)b * TD_ + m0) * TE_; // half 1

  // --- phase 1: softmax stats, one wave per row ---
  for (int rr = 0; rr < 8; ++rr) {
    const int r = w * 8 + rr;
    const float* p0 = s0 + (long)r * TE_;
    const float* p1 = s1 + (long)r * TE_;
    float x[8]; float mx = -1e30f;
#pragma unroll
    for (int k = 0; k < 8; ++k) {
      x[k] = p0[lane + 64 * k] + p1[lane + 64 * k];
      mx = fmaxf(mx, x[k]);
    }
#pragma unroll
    for (int off = 32; off; off >>= 1) mx = fmaxf(mx, __shfl_xor(mx, off, 64));
    float sum = 0.f;
#pragma unroll
    for (int k = 0; k < 8; ++k) sum += exp2_fast((x[k] - mx) * LOG2E);
#pragma unroll
    for (int off = 32; off; off >>= 1) sum += __shfl_xor(sum, off, 64);
    if (lane == 0) rowc[r] = -(mx * LOG2E) - __log2f(sum);
  }
  __syncthreads();

  const int mw = (w & 1) * 16, nw = (w >> 1) * 16;
  const int quad = lane >> 4, l16 = lane & 15;
  const int am = tid >> 3, ak = (tid & 7) * 4;
  const int bn = tid & 31, bk = (tid >> 5) * 4;
  const float c0 = rowc[am];
  const float* E = enc + (long)b * TE_ * H_;
  const bool writeAttn = (n0 == 0);
  float* arow = attn + ((long)b * TD_ + m0 + am) * TE_;

  f32x4 acc = {0.f, 0.f, 0.f, 0.f};
  for (int k0 = 0; k0 < TE_; k0 += 32) {
    // A-stage: normalized weights p = exp2(x*log2e + c0), split to bf16 hi/lo
    float4 a0 = *(const float4*)&s0[(long)am * TE_ + k0 + ak];
    float4 a1 = *(const float4*)&s1[(long)am * TE_ + k0 + ak];
    float4 p;
    p.x = exp2_fast(__fmaf_rn(a0.x + a1.x, LOG2E, c0));
    p.y = exp2_fast(__fmaf_rn(a0.y + a1.y, LOG2E, c0));
    p.z = exp2_fast(__fmaf_rn(a0.z + a1.z, LOG2E, c0));
    p.w = exp2_fast(__fmaf_rn(a0.w + a1.w, LOG2E, c0));
    unsigned short h0, l0, h1, l1, h2, l2, h3, l3;
    bf16split(p.x, h0, l0); bf16split(p.y, h1, l1);
    bf16split(p.z, h2, l2); bf16split(p.w, h3, l3);
    *(ushort4*)&Ph[am][ak] = make_ushort4(h0, h1, h2, h3);
    *(ushort4*)&Pl[am][ak] = make_ushort4(l0, l1, l2, l3);
    if (writeAttn) *(float4*)&arow[k0 + ak] = p;   // attention-weights output
    // B-stage: enc rows k0+bk..+3, col n0+bn, split to bf16 hi/lo
    float b0 = E[(long)(k0 + bk + 0) * H_ + n0 + bn];
    float b1 = E[(long)(k0 + bk + 1) * H_ + n0 + bn];
    float b2 = E[(long)(k0 + bk + 2) * H_ + n0 + bn];
    float b3 = E[(long)(k0 + bk + 3) * H_ + n0 + bn];
    bf16split(b0, h0, l0); bf16split(b1, h1, l1);
    bf16split(b2, h2, l2); bf16split(b3, h3, l3);
    *(ushort4*)&Eh[bn][bk] = make_ushort4(h0, h1, h2, h3);
    *(ushort4*)&El[bn][bk] = make_ushort4(l0, l1, l2, l3);
    __syncthreads();
    bf16x8 ph = *(const bf16x8*)&Ph[mw + l16][quad * 8];
    bf16x8 pl = *(const bf16x8*)&Pl[mw + l16][quad * 8];
    bf16x8 eh = *(const bf16x8*)&Eh[nw + l16][quad * 8];
    bf16x8 el = *(const bf16x8*)&El[nw + l16][quad * 8];
    acc = __builtin_amdgcn_mfma_f32_16x16x32_bf16(ph, eh, acc, 0, 0, 0);
    acc = __builtin_amdgcn_mfma_f32_16x16x32_bf16(ph, el, acc, 0, 0, 0);
    acc = __builtin_amdgcn_mfma_f32_16x16x32_bf16(pl, eh, acc, 0, 0, 0);
    __syncthreads();
  }
#pragma unroll
  for (int r = 0; r < 4; ++r)
    ctx[((long)b * TD_ + m0 + mw + quad * 4 + r) * H_ + n0 + nw + l16] = acc[r];
}

extern "C" void kernel_launch(void* const* d_in, const int* in_sizes, int n_in,
                              void* d_out, int out_size, void* d_ws, size_t ws_size,
                              hipStream_t stream) {
  const float* enc = (const float*)d_in[0];  // [B,TE,H]
  const float* dec = (const float*)d_in[1];  // [B,TD,H]
  const float* Wa  = (const float*)d_in[2];  // [H,H]
  const float* Ua  = (const float*)d_in[3];  // [H,H]
  const float* Va  = (const float*)d_in[4];  // [H,1]

  float* out  = (float*)d_out;
  float* ctx  = out;                           // [B,TD,H]
  float* attn = out + (long)B_ * TD_ * H_;     // [B,TD,TE]

  float* ep = (float*)d_ws;                    // [B*TE,H] prescaled by 2log2e
  float* dp = ep + (long)B_ * TE_ * H_;        // [B*TD,H] prescaled
  float* sc = dp + (long)B_ * TD_ * H_;        // [2][B,TD,TE] h-split partials

  proj_mfma<<<dim3(160, 8), 256, 0, stream>>>(enc, dec, Wa, Ua, ep, dp);
  score_kernel<<<dim3(TE_ / 32, TD_ / 16, 2 * B_), 256, 0, stream>>>(ep, dp, Va, sc);
  ctx_sm<<<dim3(TD_ / 32, H_ / 32, B_), 256, 0, stream>>>(sc, enc, attn, ctx);
}

// Round 7
// 99.384 us; speedup vs baseline: 1.1663x; 1.1663x over previous
//
#include <hip/hip_runtime.h>
#include <hip/hip_bf16.h>

#ifndef __has_builtin
#define __has_builtin(x) 0
#endif

// ---- problem constants ----
constexpr int B_ = 8, TE_ = 512, TD_ = 128, H_ = 256;
constexpr float TWO_LOG2E = 2.8853900817779268f;   // 2*log2(e)
constexpr float LOG2E = 1.4426950408889634f;

typedef float  vf2    __attribute__((ext_vector_type(2)));
typedef short  bf16x8 __attribute__((ext_vector_type(8)));
typedef float  f32x4  __attribute__((ext_vector_type(4)));

__device__ __forceinline__ float exp2_fast(float x) {
#if __has_builtin(__builtin_amdgcn_exp2f)
  return __builtin_amdgcn_exp2f(x);     // v_exp_f32 (quarter rate)
#else
  return exp2f(x);
#endif
}
__device__ __forceinline__ float rcp_fast(float x) {
#if __has_builtin(__builtin_amdgcn_rcpf)
  return __builtin_amdgcn_rcpf(x);      // v_rcp_f32 (quarter rate)
#else
  return 1.0f / x;
#endif
}
__device__ __forceinline__ vf2 fma2(vf2 a, vf2 b, vf2 c) {
#if __has_builtin(__builtin_elementwise_fma)
  return __builtin_elementwise_fma(a, b, c);   // v_pk_fma_f32
#else
  vf2 r; r.x = __fmaf_rn(a.x, b.x, c.x); r.y = __fmaf_rn(a.y, b.y, c.y); return r;
#endif
}
// split fp32 -> bf16 hi + bf16 lo (x ~= hi + lo to ~2^-16 rel)
__device__ __forceinline__ void bf16split(float x, unsigned short& hi, unsigned short& lo) {
  unsigned u = __float_as_uint(x);
  hi = (unsigned short)(u >> 16);
  float hif = __uint_as_float((unsigned)hi << 16);
  lo = (unsigned short)(__float_as_uint(x - hif) >> 16);
}

// ============== MFMA projection: ep=exp2((enc@W)*2log2e), dp=exp2((dec@U)*2log2e) ==============
// Split-bf16 (3 products). Block tile 32m x 32n, 4 waves, K chunks of 32.
// grid (160, 8) = 1280 blocks. Epilogue exp2 moves the per-score-element exp2
// (134M evals) to the projection (1.6M evals): t = exp2(ep'+dp') = E*D.
__global__ __launch_bounds__(256)
void proj_mfma(const float* __restrict__ enc, const float* __restrict__ dec,
               const float* __restrict__ W, const float* __restrict__ U,
               float* __restrict__ ep, float* __restrict__ dp) {
  __shared__ unsigned short Ah[32][40], Al[32][40], Bh[32][40], Bl[32][40];
  const int tid = threadIdx.x;
  const int mt = blockIdx.x;
  const int n0 = blockIdx.y * 32;
  const float* A; const float* Bm; float* C; int row0;
  if (mt < 128) { A = enc; Bm = W; C = ep; row0 = mt * 32; }
  else          { A = dec; Bm = U; C = dp; row0 = (mt - 128) * 32; }
  const int w = tid >> 6, lane = tid & 63;
  const int mw = (w & 1) * 16, nw = (w >> 1) * 16;
  const int quad = lane >> 4, l16 = lane & 15;
  const int am = tid >> 3, ak = (tid & 7) * 4;
  const int bn = tid & 31, bk = (tid >> 5) * 4;

  f32x4 acc = {0.f, 0.f, 0.f, 0.f};
  for (int k0 = 0; k0 < H_; k0 += 32) {
    float4 a4 = *(const float4*)&A[(long)(row0 + am) * H_ + k0 + ak];
    unsigned short h0, l0, h1, l1, h2, l2, h3, l3;
    bf16split(a4.x, h0, l0); bf16split(a4.y, h1, l1);
    bf16split(a4.z, h2, l2); bf16split(a4.w, h3, l3);
    *(ushort4*)&Ah[am][ak] = make_ushort4(h0, h1, h2, h3);
    *(ushort4*)&Al[am][ak] = make_ushort4(l0, l1, l2, l3);
    float b0 = Bm[(long)(k0 + bk + 0) * H_ + n0 + bn];
    float b1 = Bm[(long)(k0 + bk + 1) * H_ + n0 + bn];
    float b2 = Bm[(long)(k0 + bk + 2) * H_ + n0 + bn];
    float b3 = Bm[(long)(k0 + bk + 3) * H_ + n0 + bn];
    bf16split(b0, h0, l0); bf16split(b1, h1, l1);
    bf16split(b2, h2, l2); bf16split(b3, h3, l3);
    *(ushort4*)&Bh[bn][bk] = make_ushort4(h0, h1, h2, h3);
    *(ushort4*)&Bl[bn][bk] = make_ushort4(l0, l1, l2, l3);
    __syncthreads();
    bf16x8 ah = *(const bf16x8*)&Ah[mw + l16][quad * 8];
    bf16x8 al = *(const bf16x8*)&Al[mw + l16][quad * 8];
    bf16x8 bh = *(const bf16x8*)&Bh[nw + l16][quad * 8];
    bf16x8 bl = *(const bf16x8*)&Bl[nw + l16][quad * 8];
    acc = __builtin_amdgcn_mfma_f32_16x16x32_bf16(ah, bh, acc, 0, 0, 0);
    acc = __builtin_amdgcn_mfma_f32_16x16x32_bf16(ah, bl, acc, 0, 0, 0);
    acc = __builtin_amdgcn_mfma_f32_16x16x32_bf16(al, bh, acc, 0, 0, 0);
    __syncthreads();
  }
#pragma unroll
  for (int r = 0; r < 4; ++r)
    C[(long)(row0 + mw + quad * 4 + r) * H_ + n0 + nw + l16] =
        exp2_fast(acc[r] * TWO_LOG2E);
}

// ================= score kernel: t = E*D (no per-elem exp2) =================
// sc_partial[hs][b,d,e] = sum_{h in half} (-2 v_h) * rcp(1 + E[e,h]*D[d,h])
// == tanh-sum minus const shift (invisible to softmax). Exact vs tanh to fp32 rounding.
// Tiles 32e x 16d, 256 threads (1e x 2d), grid (16,8,16) = 2048 blocks (8/CU).
__global__ __launch_bounds__(256)
void score_kernel(const float* __restrict__ ep, const float* __restrict__ dp,
                  const float* __restrict__ v, float* __restrict__ sc) {
  __shared__ __align__(16) float eps[32][68];
  __shared__ __align__(16) float dps[16][68];
  __shared__ __align__(16) float vs[64];
  const int tid = threadIdx.x;
  const int bz = blockIdx.z;
  const int b = bz >> 1;
  const int h_lo = (bz & 1) * 128;
  const int e0 = blockIdx.x * 32;
  const int d0 = blockIdx.y * 16;
  const int e = tid & 31;
  const int dg = tid >> 5;
  vf2 acc0 = {0.f, 0.f}, acc1 = {0.f, 0.f};

  for (int h0 = h_lo; h0 < h_lo + 128; h0 += 64) {
#pragma unroll
    for (int i = 0; i < 2; ++i) {
      int idx = tid + i * 256;
      int r = idx >> 4, c = (idx & 15) << 2;
      *(float4*)&eps[r][c] = *(const float4*)&ep[(long)(b * TE_ + e0 + r) * H_ + h0 + c];
    }
    {
      int r = tid >> 4, c = (tid & 15) << 2;
      *(float4*)&dps[r][c] = *(const float4*)&dp[(long)(b * TD_ + d0 + r) * H_ + h0 + c];
    }
    if (tid < 16) {
      float4 v4 = *(const float4*)&v[h0 + tid * 4];
      float4 o; o.x = -2.f * v4.x; o.y = -2.f * v4.y; o.z = -2.f * v4.z; o.w = -2.f * v4.w;
      *(float4*)&vs[tid * 4] = o;
    }
    __syncthreads();
    const vf2 one2 = {1.f, 1.f};
#pragma unroll
    for (int hh = 0; hh < 64; hh += 4) {
      float4 evf = *(const float4*)&eps[e][hh];       // E values
      float4 vvf = *(const float4*)&vs[hh];
      float4 daf = *(const float4*)&dps[dg * 2 + 0][hh];  // D row 0
      float4 dbf = *(const float4*)&dps[dg * 2 + 1][hh];  // D row 1
      vf2 ev0 = {evf.x, evf.y}, ev1 = {evf.z, evf.w};
      vf2 vv0 = {vvf.x, vvf.y}, vv1 = {vvf.z, vvf.w};
      vf2 da0 = {daf.x, daf.y}, da1 = {daf.z, daf.w};
      vf2 db0 = {dbf.x, dbf.y}, db1 = {dbf.z, dbf.w};
      vf2 t0 = ev0 * da0 + one2;   // v_pk_fma: E*D + 1
      vf2 t1 = ev1 * da1 + one2;
      vf2 u0 = ev0 * db0 + one2;
      vf2 u1 = ev1 * db1 + one2;
      vf2 r0, r1, s0, s1;
      r0.x = rcp_fast(t0.x); r0.y = rcp_fast(t0.y);
      r1.x = rcp_fast(t1.x); r1.y = rcp_fast(t1.y);
      s0.x = rcp_fast(u0.x); s0.y = rcp_fast(u0.y);
      s1.x = rcp_fast(u1.x); s1.y = rcp_fast(u1.y);
      acc0 = fma2(vv0, r0, acc0); acc0 = fma2(vv1, r1, acc0);
      acc1 = fma2(vv0, s0, acc1); acc1 = fma2(vv1, s1, acc1);
    }
    __syncthreads();
  }
  long base = ((long)(bz & 1) * B_ * TD_ + (long)b * TD_ + d0 + dg * 2) * TE_ + e0 + e;
  sc[base] = acc0.x + acc0.y;
  sc[base + TE_] = acc1.x + acc1.y;
}

// ====== softmax: attn row = softmax(sc_half0 + sc_half1), one wave per row ======
__global__ __launch_bounds__(64)
void softmax_kernel(const float* __restrict__ sc, float* __restrict__ attn) {
  const long row = blockIdx.x;
  const float* p0 = sc + row * TE_;
  const float* p1 = sc + ((long)B_ * TD_ + row) * TE_;
  float* pout = attn + row * TE_;
  const int t = threadIdx.x;
  float x[8];
  float m = -1e30f;
#pragma unroll
  for (int k = 0; k < 8; ++k) {
    x[k] = p0[t + 64 * k] + p1[t + 64 * k];
    m = fmaxf(m, x[k]);
  }
#pragma unroll
  for (int off = 32; off; off >>= 1) m = fmaxf(m, __shfl_xor(m, off, 64));
  float s = 0.f;
#pragma unroll
  for (int k = 0; k < 8; ++k) { x[k] = exp2_fast((x[k] - m) * LOG2E); s += x[k]; }
#pragma unroll
  for (int off = 32; off; off >>= 1) s += __shfl_xor(s, off, 64);
  const float r = rcp_fast(s);
#pragma unroll
  for (int k = 0; k < 8; ++k) pout[t + 64 * k] = x[k] * r;
}

// ================= MFMA context: ctx[b] = attn[b] @ enc[b] =================
// M=128, N=256, K=512 per batch. Block tile 32m x 32n, K chunks of 32.
// grid (4, 8, 8) = 256 blocks. Split-bf16 3-product scheme.
__global__ __launch_bounds__(256)
void ctx_mfma(const float* __restrict__ attn, const float* __restrict__ enc,
              float* __restrict__ ctx) {
  __shared__ unsigned short Ah[32][40], Al[32][40], Bh[32][40], Bl[32][40];
  const int tid = threadIdx.x;
  const int m0 = blockIdx.x * 32;
  const int n0 = blockIdx.y * 32;
  const int b = blockIdx.z;
  const float* A = attn + (long)b * TD_ * TE_;
  const float* E = enc + (long)b * TE_ * H_;
  const int w = tid >> 6, lane = tid & 63;
  const int mw = (w & 1) * 16, nw = (w >> 1) * 16;
  const int quad = lane >> 4, l16 = lane & 15;
  const int am = tid >> 3, ak = (tid & 7) * 4;
  const int bn = tid & 31, bk = (tid >> 5) * 4;

  f32x4 acc = {0.f, 0.f, 0.f, 0.f};
  for (int k0 = 0; k0 < TE_; k0 += 32) {
    float4 a4 = *(const float4*)&A[(long)(m0 + am) * TE_ + k0 + ak];
    unsigned short h0, l0, h1, l1, h2, l2, h3, l3;
    bf16split(a4.x, h0, l0); bf16split(a4.y, h1, l1);
    bf16split(a4.z, h2, l2); bf16split(a4.w, h3, l3);
    *(ushort4*)&Ah[am][ak] = make_ushort4(h0, h1, h2, h3);
    *(ushort4*)&Al[am][ak] = make_ushort4(l0, l1, l2, l3);
    float b0 = E[(long)(k0 + bk + 0) * H_ + n0 + bn];
    float b1 = E[(long)(k0 + bk + 1) * H_ + n0 + bn];
    float b2 = E[(long)(k0 + bk + 2) * H_ + n0 + bn];
    float b3 = E[(long)(k0 + bk + 3) * H_ + n0 + bn];
    bf16split(b0, h0, l0); bf16split(b1, h1, l1);
    bf16split(b2, h2, l2); bf16split(b3, h3, l3);
    *(ushort4*)&Bh[bn][bk] = make_ushort4(h0, h1, h2, h3);
    *(ushort4*)&Bl[bn][bk] = make_ushort4(l0, l1, l2, l3);
    __syncthreads();
    bf16x8 ah = *(const bf16x8*)&Ah[mw + l16][quad * 8];
    bf16x8 al = *(const bf16x8*)&Al[mw + l16][quad * 8];
    bf16x8 bh = *(const bf16x8*)&Bh[nw + l16][quad * 8];
    bf16x8 bl = *(const bf16x8*)&Bl[nw + l16][quad * 8];
    acc = __builtin_amdgcn_mfma_f32_16x16x32_bf16(ah, bh, acc, 0, 0, 0);
    acc = __builtin_amdgcn_mfma_f32_16x16x32_bf16(ah, bl, acc, 0, 0, 0);
    acc = __builtin_amdgcn_mfma_f32_16x16x32_bf16(al, bh, acc, 0, 0, 0);
    __syncthreads();
  }
#pragma unroll
  for (int r = 0; r < 4; ++r)
    ctx[((long)b * TD_ + m0 + mw + quad * 4 + r) * H_ + n0 + nw + l16] = acc[r];
}

extern "C" void kernel_launch(void* const* d_in, const int* in_sizes, int n_in,
                              void* d_out, int out_size, void* d_ws, size_t ws_size,
                              hipStream_t stream) {
  const float* enc = (const float*)d_in[0];  // [B,TE,H]
  const float* dec = (const float*)d_in[1];  // [B,TD,H]
  const float* Wa  = (const float*)d_in[2];  // [H,H]
  const float* Ua  = (const float*)d_in[3];  // [H,H]
  const float* Va  = (const float*)d_in[4];  // [H,1]

  float* out  = (float*)d_out;
  float* ctx  = out;                           // [B,TD,H]
  float* attn = out + (long)B_ * TD_ * H_;     // [B,TD,TE]

  float* ep = (float*)d_ws;                    // [B*TE,H] = exp2(proj*2log2e)
  float* dp = ep + (long)B_ * TE_ * H_;        // [B*TD,H] = exp2(proj*2log2e)
  float* sc = dp + (long)B_ * TD_ * H_;        // [2][B,TD,TE] h-split partials

  proj_mfma<<<dim3(160, 8), 256, 0, stream>>>(enc, dec, Wa, Ua, ep, dp);
  score_kernel<<<dim3(TE_ / 32, TD_ / 16, 2 * B_), 256, 0, stream>>>(ep, dp, Va, sc);
  softmax_kernel<<<dim3(B_ * TD_), 64, 0, stream>>>(sc, attn);
  ctx_mfma<<<dim3(TD_ / 32, H_ / 32, B_), 256, 0, stream>>>(attn, enc, ctx);
}